// Round 1
// baseline (5679.443 us; speedup 1.0000x reference)
//
#include <hip/hip_runtime.h>
#include <math.h>

#define AS1 __attribute__((address_space(1)))
#define AS3 __attribute__((address_space(3)))
typedef unsigned short ushort_t;
typedef __attribute__((ext_vector_type(8))) short short8;
typedef __attribute__((ext_vector_type(4))) float f32x4;

// ---------- bf16 helpers (bit-level, RNE) ----------
__device__ __forceinline__ ushort_t f2bf(float f) {
  unsigned u = __float_as_uint(f);
  u += 0x7fffu + ((u >> 16) & 1u);
  return (ushort_t)(u >> 16);
}
__device__ __forceinline__ float bf2f(ushort_t s) { return __uint_as_float(((unsigned)s) << 16); }
__device__ __forceinline__ void split_store(float v, ushort_t* hi, ushort_t* lo, int idx) {
  ushort_t h = f2bf(v);
  hi[idx] = h;
  lo[idx] = f2bf(v - bf2f(h));
}
__device__ __forceinline__ float sigm(float x) { return 1.0f / (1.0f + __expf(-x)); }

// ---------- elementwise prep kernels ----------
__global__ void conv_bf16(const float* __restrict__ src, ushort_t* __restrict__ dst, int n) {
  int i = (blockIdx.x * 256 + threadIdx.x) * 4;
  if (i >= n) return;
  float4 v = *(const float4*)(src + i);
  ushort4 q;
  q.x = f2bf(v.x); q.y = f2bf(v.y); q.z = f2bf(v.z); q.w = f2bf(v.w);
  *(ushort4*)(dst + i) = q;
}

// X[t*64+b][e] = emb[tok][e]*sqrt(EMB), stored as hi/lo bf16 split
__global__ void embed_split_k(const int* __restrict__ toks, const float* __restrict__ emb,
                              ushort_t* __restrict__ Xhi, ushort_t* __restrict__ Xlo) {
  int row = blockIdx.x;           // t*64+b
  int tok = toks[row];
  int e = threadIdx.x * 4;
  float4 v = *(const float4*)(emb + (size_t)tok * 1024 + e);
  float a[4] = {v.x * 32.0f, v.y * 32.0f, v.z * 32.0f, v.w * 32.0f};
  ushort4 h, l;
  h.x = f2bf(a[0]); l.x = f2bf(a[0] - bf2f(h.x));
  h.y = f2bf(a[1]); l.y = f2bf(a[1] - bf2f(h.y));
  h.z = f2bf(a[2]); l.z = f2bf(a[2] - bf2f(h.z));
  h.w = f2bf(a[3]); l.w = f2bf(a[3] - bf2f(h.w));
  *(ushort4*)(Xhi + (size_t)row * 1024 + e) = h;
  *(ushort4*)(Xlo + (size_t)row * 1024 + e) = l;
}

__global__ void init_state_k(const float* __restrict__ hid, float* h0, float* h1,
                             ushort_t* h0hi, ushort_t* h0lo, ushort_t* h1hi, ushort_t* h1lo) {
  int i = blockIdx.x * 256 + threadIdx.x;   // 0..65535  (= b*1024+n)
  float a = hid[i], b = hid[65536 + i];
  h0[i] = a; h1[i] = b;
  split_store(a, h0hi, h0lo, i);
  split_store(b, h1hi, h1lo, i);
}

__global__ void final_copy_k(const float* __restrict__ h0, const float* __restrict__ h1,
                             float* __restrict__ dst) {
  int i = blockIdx.x * 256 + threadIdx.x;
  dst[i] = h0[i];
  dst[65536 + i] = h1[i];
}

// ---------- big MFMA GEMM: C(MxN,f32) = A(MxK,bf16)@B(NxK,bf16)^T (+A2 pass) (+bias) ----------
// 128x128 tile, 256 thr = 4 waves (2x2), each wave 64x64 via 4x4 tiles of 16x16x32.
// LDS layout XOR-swizzled in 16B chunks: row r chunk c stored at slot (c ^ (r&7)).
__global__ __launch_bounds__(256) void gemm_bt(const ushort_t* __restrict__ A, const ushort_t* __restrict__ A2,
                                               const ushort_t* __restrict__ B, float* __restrict__ C,
                                               int M, int N, int K, const float* __restrict__ bias) {
  __shared__ ushort_t As[128 * 64];
  __shared__ ushort_t Bs[128 * 64];
  int tid = threadIdx.x, w = tid >> 6, lane = tid & 63;
  int mtiles = M >> 7;
  int mt = blockIdx.x % mtiles, nt = blockIdx.x / mtiles;
  int row0 = mt << 7, col0 = nt << 7;
  int wm = w & 1, wn = w >> 1;
  f32x4 zero = {0.f, 0.f, 0.f, 0.f};
  f32x4 acc[4][4];
#pragma unroll
  for (int i = 0; i < 4; ++i)
#pragma unroll
    for (int j = 0; j < 4; ++j) acc[i][j] = zero;

  int cd = (lane & 7) ^ (lane >> 3);            // swizzled source chunk for this lane
  const ushort_t* Bsrc = B + (size_t)(col0 + w * 32 + (lane >> 3)) * K + cd * 8;
  AS3 char* AsD = (AS3 char*)As + w * 4096;
  AS3 char* BsD = (AS3 char*)Bs + w * 4096;
  int ktiles = K >> 6;

  for (int pass = 0; pass < 2; ++pass) {
    const ushort_t* Ap = pass ? A2 : A;
    if (!Ap) break;
    const ushort_t* Asrc = Ap + (size_t)(row0 + w * 32 + (lane >> 3)) * K + cd * 8;
    for (int kt = 0; kt < ktiles; ++kt) {
      int k0 = kt << 6;
      __syncthreads();
#pragma unroll
      for (int i = 0; i < 4; ++i) {
        __builtin_amdgcn_global_load_lds((const AS1 void*)(Asrc + (size_t)i * 8 * K + k0),
                                         (AS3 void*)(AsD + i * 1024), 16, 0, 0);
        __builtin_amdgcn_global_load_lds((const AS1 void*)(Bsrc + (size_t)i * 8 * K + k0),
                                         (AS3 void*)(BsD + i * 1024), 16, 0, 0);
      }
      __syncthreads();
#pragma unroll
      for (int kk = 0; kk < 2; ++kk) {
        short8 af[4], bfr[4];
        int c = kk * 4 + (lane >> 4);
#pragma unroll
        for (int i = 0; i < 4; ++i) {
          int r = wm * 64 + i * 16 + (lane & 15);
          af[i] = *(const short8*)&As[(r * 8 + (c ^ (r & 7))) * 8];
        }
#pragma unroll
        for (int j = 0; j < 4; ++j) {
          int rB = wn * 64 + j * 16 + (lane & 15);
          bfr[j] = *(const short8*)&Bs[(rB * 8 + (c ^ (rB & 7))) * 8];
        }
#pragma unroll
        for (int i = 0; i < 4; ++i)
#pragma unroll
          for (int j = 0; j < 4; ++j)
            acc[i][j] = __builtin_amdgcn_mfma_f32_16x16x32_bf16(af[i], bfr[j], acc[i][j], 0, 0, 0);
      }
    }
  }
  // epilogue: C/D layout col=lane&15, row=(lane>>4)*4+r
#pragma unroll
  for (int i = 0; i < 4; ++i) {
#pragma unroll
    for (int j = 0; j < 4; ++j) {
      int n = col0 + wn * 64 + j * 16 + (lane & 15);
      float bv = bias ? bias[n] : 0.0f;
#pragma unroll
      for (int r = 0; r < 4; ++r) {
        int m = row0 + wm * 64 + i * 16 + (lane >> 4) * 4 + r;
        C[(size_t)m * N + n] = acc[i][j][r] + bv;
      }
    }
  }
}

// ---------- recurrence phase kernel ----------
// Grid = 96 blocks: group g = bx>>5 (3 groups of 1024 cols), 32-col tile each.
// alpha(t): g0: htil0 = G0+rp0@Uh0^T+bh0 -> h0,ht0 ; g1: reset1 -> rp1 ; g2: forget1 -> z1
// beta(t) : g0: htil1 -> h1,Htop ; g1: reset0(t+1) -> rs0,rp0 ; g2: forget0(t+1) -> fg0,z0
// A-side uses hi+lo bf16 split (fp32-equivalent), weights plain bf16.
struct PhaseParams {
  const ushort_t *Wr1, *Wf1, *Wh1, *Ur0, *Uf0, *Uh0, *Ur1, *Uf1, *Uh1;
  const float *G0, *br, *bf, *bh;
  float *h0, *h1, *z0, *z1;
  ushort_t *h0hi, *h0lo, *h1hi, *h1lo, *rp0hi, *rp0lo, *rs0hi, *rs0lo,
           *fg0hi, *fg0lo, *ht0hi, *ht0lo, *rp1hi, *rp1lo, *Htop;
};

__global__ __launch_bounds__(256) void phase_kernel(PhaseParams P, int t, int isBeta, int mode) {
  __shared__ ushort_t Bs[32 * 64];
  int g = blockIdx.x >> 5, ct = blockIdx.x & 31;
  if (mode == 1 && g == 0) return;   // beta(-1): only reset0/forget0
  if (mode == 2 && g != 0) return;   // beta(63): only htil1
  int tid = threadIdx.x, w = tid >> 6, lane = tid & 63;
  int nc = ct * 32;
  const ushort_t *A0h, *A0l, *W0, *A1h = nullptr, *A1l = nullptr, *W1 = nullptr;
  if (!isBeta) {
    if (g == 0)      { A0h = P.rp0hi; A0l = P.rp0lo; W0 = P.Uh0; }
    else if (g == 1) { A0h = P.rs0hi; A0l = P.rs0lo; W0 = P.Wr1; A1h = P.h1hi; A1l = P.h1lo; W1 = P.Ur1; }
    else             { A0h = P.fg0hi; A0l = P.fg0lo; W0 = P.Wf1; A1h = P.h1hi; A1l = P.h1lo; W1 = P.Uf1; }
  } else {
    if (g == 0)      { A0h = P.ht0hi; A0l = P.ht0lo; W0 = P.Wh1; A1h = P.rp1hi; A1l = P.rp1lo; W1 = P.Uh1; }
    else if (g == 1) { A0h = P.h0hi;  A0l = P.h0lo;  W0 = P.Ur0; }
    else             { A0h = P.h0hi;  A0l = P.h0lo;  W0 = P.Uf0; }
  }
  f32x4 zero = {0.f, 0.f, 0.f, 0.f};
  f32x4 acc[2]; acc[0] = zero; acc[1] = zero;
  int rl = w * 8 + (lane >> 3);
  int cd = (lane & 7) ^ (lane >> 3);
  AS3 char* BsD = (AS3 char*)Bs + w * 1024;
  int mrow = w * 16 + (lane & 15);
  int kq = (lane >> 4) * 8;

  for (int term = 0; term < 2; ++term) {
    const ushort_t* Ah = term ? A1h : A0h;
    const ushort_t* Al = term ? A1l : A0l;
    const ushort_t* Wt = term ? W1 : W0;
    if (!Wt) break;
    const ushort_t* Bsrc = Wt + (size_t)(nc + rl) * 1024 + cd * 8;
    for (int kt = 0; kt < 16; ++kt) {
      int k0 = kt << 6;
      __syncthreads();
      __builtin_amdgcn_global_load_lds((const AS1 void*)(Bsrc + k0), (AS3 void*)BsD, 16, 0, 0);
      __syncthreads();
      short8 bfr[2][2];
#pragma unroll
      for (int j = 0; j < 2; ++j)
#pragma unroll
        for (int kk = 0; kk < 2; ++kk) {
          int rB = j * 16 + (lane & 15);
          int c = kk * 4 + (lane >> 4);
          bfr[j][kk] = *(const short8*)&Bs[(rB * 8 + (c ^ (rB & 7))) * 8];
        }
#pragma unroll
      for (int sp = 0; sp < 2; ++sp) {
        const ushort_t* Apt = sp ? Al : Ah;
#pragma unroll
        for (int kk = 0; kk < 2; ++kk) {
          short8 af = *(const short8*)(Apt + (size_t)mrow * 1024 + k0 + kk * 32 + kq);
          acc[0] = __builtin_amdgcn_mfma_f32_16x16x32_bf16(af, bfr[0][kk], acc[0], 0, 0, 0);
          acc[1] = __builtin_amdgcn_mfma_f32_16x16x32_bf16(af, bfr[1][kk], acc[1], 0, 0, 0);
        }
      }
    }
  }
  // fused epilogues
#pragma unroll
  for (int j = 0; j < 2; ++j) {
    int n = nc + j * 16 + (lane & 15);
#pragma unroll
    for (int r = 0; r < 4; ++r) {
      int m = w * 16 + (lane >> 4) * 4 + r;
      int idx = m * 1024 + n;
      float v = acc[j][r];
      if (!isBeta) {
        if (g == 0) {                      // htil0 -> h0
          float pre = v + P.G0[(size_t)(t * 64 + m) * 1024 + n] + P.bh[n];
          float z = P.z0[idx];
          float hn = (1.f - z) * P.h0[idx] + z * tanhf(pre);
          P.h0[idx] = hn;
          split_store(hn, P.h0hi, P.h0lo, idx);
          split_store(pre, P.ht0hi, P.ht0lo, idx);
        } else if (g == 1) {               // reset1 -> rp1
          float pre = v + P.br[1024 + n];
          split_store(sigm(pre) * P.h1[idx], P.rp1hi, P.rp1lo, idx);
        } else {                           // forget1 -> z1
          P.z1[idx] = sigm(v + P.bf[1024 + n]);
        }
      } else {
        if (g == 0) {                      // htil1 -> h1, Htop
          float pre = v + P.bh[1024 + n];
          float z = P.z1[idx];
          float hn = (1.f - z) * P.h1[idx] + z * tanhf(pre);
          P.h1[idx] = hn;
          split_store(hn, P.h1hi, P.h1lo, idx);
          P.Htop[(size_t)(t * 64 + m) * 1024 + n] = f2bf(hn);
        } else if (g == 1) {               // reset0(t+1) -> rs0, rp0
          float pre = v + P.G0[(size_t)((t + 1) * 64 + m) * 1024 + n] + P.br[n];
          split_store(pre, P.rs0hi, P.rs0lo, idx);
          split_store(sigm(pre) * P.h0[idx], P.rp0hi, P.rp0lo, idx);
        } else {                           // forget0(t+1) -> fg0, z0
          float pre = v + P.G0[(size_t)((t + 1) * 64 + m) * 1024 + n] + P.bf[n];
          split_store(pre, P.fg0hi, P.fg0lo, idx);
          P.z0[idx] = sigm(pre);
        }
      }
    }
  }
}

// ---------- host ----------
extern "C" void kernel_launch(void* const* d_in, const int* in_sizes, int n_in,
                              void* d_out, int out_size, void* d_ws, size_t ws_size,
                              hipStream_t stream) {
  (void)in_sizes; (void)n_in; (void)out_size; (void)ws_size;
  const int*   toks = (const int*)d_in[0];
  const float* hid  = (const float*)d_in[1];
  const float* emb  = (const float*)d_in[2];
  const float* W_in = (const float*)d_in[3];
  const float* Wr1  = (const float*)d_in[4];
  const float* Wf1  = (const float*)d_in[5];
  const float* Wh1  = (const float*)d_in[6];
  const float* Ur   = (const float*)d_in[7];
  const float* br   = (const float*)d_in[8];
  const float* Uf   = (const float*)d_in[9];
  const float* bfp  = (const float*)d_in[10];
  const float* Uh   = (const float*)d_in[11];
  const float* bh   = (const float*)d_in[12];
  const float* outW = (const float*)d_in[13];
  const float* outb = (const float*)d_in[14];
  float* out = (float*)d_out;

  char* ws = (char*)d_ws;
  size_t off = 0;
  auto alloc = [&](size_t bytes) { char* p = ws + off; off += (bytes + 255) & ~(size_t)255; return p; };
  ushort_t* Xhi    = (ushort_t*)alloc((size_t)4096 * 1024 * 2);
  ushort_t* Xlo    = (ushort_t*)alloc((size_t)4096 * 1024 * 2);
  float*    G0     = (float*)alloc((size_t)4096 * 1024 * 4);
  ushort_t* WinB   = (ushort_t*)alloc((size_t)1024 * 1024 * 2);
  ushort_t* Wr1B   = (ushort_t*)alloc((size_t)1024 * 1024 * 2);
  ushort_t* Wf1B   = (ushort_t*)alloc((size_t)1024 * 1024 * 2);
  ushort_t* Wh1B   = (ushort_t*)alloc((size_t)1024 * 1024 * 2);
  ushort_t* UrB    = (ushort_t*)alloc((size_t)2 * 1024 * 1024 * 2);
  ushort_t* UfB    = (ushort_t*)alloc((size_t)2 * 1024 * 1024 * 2);
  ushort_t* UhB    = (ushort_t*)alloc((size_t)2 * 1024 * 1024 * 2);
  ushort_t* outWB  = (ushort_t*)alloc((size_t)32000 * 1024 * 2);
  ushort_t* Htop   = (ushort_t*)alloc((size_t)4096 * 1024 * 2);
  float* h0 = (float*)alloc(65536 * 4);
  float* h1 = (float*)alloc(65536 * 4);
  float* z0 = (float*)alloc(65536 * 4);
  float* z1 = (float*)alloc(65536 * 4);
  ushort_t* sb[14];
  for (int i = 0; i < 14; ++i) sb[i] = (ushort_t*)alloc(65536 * 2);
  ushort_t *h0hi = sb[0], *h0lo = sb[1], *h1hi = sb[2], *h1lo = sb[3], *rp0hi = sb[4], *rp0lo = sb[5],
           *rs0hi = sb[6], *rs0lo = sb[7], *fg0hi = sb[8], *fg0lo = sb[9], *ht0hi = sb[10], *ht0lo = sb[11],
           *rp1hi = sb[12], *rp1lo = sb[13];

  // weight conversions (one-time per call, all parallel)
  conv_bf16<<<1024, 256, 0, stream>>>(W_in, WinB, 1 << 20);
  conv_bf16<<<1024, 256, 0, stream>>>(Wr1, Wr1B, 1 << 20);
  conv_bf16<<<1024, 256, 0, stream>>>(Wf1, Wf1B, 1 << 20);
  conv_bf16<<<1024, 256, 0, stream>>>(Wh1, Wh1B, 1 << 20);
  conv_bf16<<<2048, 256, 0, stream>>>(Ur, UrB, 1 << 21);
  conv_bf16<<<2048, 256, 0, stream>>>(Uf, UfB, 1 << 21);
  conv_bf16<<<2048, 256, 0, stream>>>(Uh, UhB, 1 << 21);
  conv_bf16<<<32000, 256, 0, stream>>>(outW, outWB, 32000 * 1024);

  embed_split_k<<<4096, 256, 0, stream>>>(toks, emb, Xhi, Xlo);
  // G0 = X@W_in^T for all timesteps (hi/lo split -> fp32-equivalent)
  gemm_bt<<<256, 256, 0, stream>>>(Xhi, Xlo, WinB, G0, 4096, 1024, 1024, nullptr);
  init_state_k<<<256, 256, 0, stream>>>(hid, h0, h1, h0hi, h0lo, h1hi, h1lo);

  PhaseParams P;
  P.Wr1 = Wr1B; P.Wf1 = Wf1B; P.Wh1 = Wh1B;
  P.Ur0 = UrB; P.Ur1 = UrB + (1 << 20);
  P.Uf0 = UfB; P.Uf1 = UfB + (1 << 20);
  P.Uh0 = UhB; P.Uh1 = UhB + (1 << 20);
  P.G0 = G0; P.br = br; P.bf = bfp; P.bh = bh;
  P.h0 = h0; P.h1 = h1; P.z0 = z0; P.z1 = z1;
  P.h0hi = h0hi; P.h0lo = h0lo; P.h1hi = h1hi; P.h1lo = h1lo;
  P.rp0hi = rp0hi; P.rp0lo = rp0lo; P.rs0hi = rs0hi; P.rs0lo = rs0lo;
  P.fg0hi = fg0hi; P.fg0lo = fg0lo; P.ht0hi = ht0hi; P.ht0lo = ht0lo;
  P.rp1hi = rp1hi; P.rp1lo = rp1lo; P.Htop = Htop;

  // beta(-1): computes reset0/forget0 pre-acts (incl. h_init recurrent term), rp0, z0 for t=0
  phase_kernel<<<96, 256, 0, stream>>>(P, -1, 1, 1);
  for (int t = 0; t < 64; ++t) {
    phase_kernel<<<96, 256, 0, stream>>>(P, t, 0, 0);
    phase_kernel<<<96, 256, 0, stream>>>(P, t, 1, (t == 63) ? 2 : 0);
  }

  // logits = Htop @ out_W^T + out_b  (4096 x 32000 x 1024)
  gemm_bt<<<8000, 256, 0, stream>>>(Htop, nullptr, outWB, out, 4096, 32000, 1024, outb);
  // final hidden states (L, BATCH, HID) flattened
  final_copy_k<<<256, 256, 0, stream>>>(h0, h1, out + (size_t)131072000);
}